// Round 2
// baseline (284.693 us; speedup 1.0000x reference)
//
#include <hip/hip_runtime.h>

typedef float v4f __attribute__((ext_vector_type(4)));

#define NB   32     // batch
#define NT   8      // timesteps
#define NC   128    // channels
#define NQ   256    // float4s per (H*W)=1024 plane
#define CRED 32     // C/red
#define PADI 32     // ints of padding per arrival counter (128 B line)

// Cross-block mean publish: each channel mean (double) is split into two
// 64-bit words:  word = (seq << 32) | 32-bit-half-of-double-bits, seq = t+1.
// Data and version share ONE atomic location, so a consumer that matches
// seq==t+1 is guaranteed fresh data regardless of whether vmcnt store-ack
// means "LLC-complete" (the R0 failure: arrive-counter and data stores to
// different LLC slices could be observed out of order; the parallel fetch
// widened that window ~30x vs the old serial consumer and tripped it).
// Double-buffered by (t&1) for WAR safety (arrive barrier provides the
// ordering proof, unchanged). NWORDS zeroed per launch so seq=0 is invalid
// across graph replays.
#define NWORDS (2 * NB * NC * 2)   // dbuf x batch x channel x {lo,hi}

__device__ int                g_arrive[NB * PADI];   // per-batch arrival counters
__device__ unsigned long long g_xw[NWORDS];          // (seq<<32 | half) words

__global__ __launch_bounds__(256)
void lif_init() {
    int i = threadIdx.x + blockIdx.x * blockDim.x;
    if (i < NWORDS) g_xw[i] = 0ull;
    if (i < NB * PADI) g_arrive[i] = 0;
}

// ---------------------------------------------------------------------------
// Single persistent kernel, plain launch. 1024 blocks (one per (b, 4-channel
// group)), 256 threads; mem state in registers. Per step: fused
// fma/spike/reset/store + plane-mean publish (seq-tagged LLC atomic words),
// per-batch 32-arrival barrier (relaxed atomics, NO fences), then a
// seq-validated 256-lane parallel fetch into LDS and a redundant per-block
// 128->32->1 MLP for the next tau. Mean double bits are reassembled exactly,
// so tau is bit-identical to the previously harness-verified kernel.
// ---------------------------------------------------------------------------
__global__ __launch_bounds__(256, 4)
void dynamic_lif(const float* __restrict__ x,
                 const float* __restrict__ w1,
                 const float* __restrict__ b1,
                 const float* __restrict__ w2,
                 const float* __restrict__ b2,
                 float* __restrict__ out)
{
    const int bid = blockIdx.x;          // 0..1023
    const int b   = bid >> 5;            // batch
    const int c0  = (bid & 31) << 2;     // first of 4 channels
    const int tid = threadIdx.x;
    const int wv  = tid >> 6;
    const int ln  = tid & 63;

    __shared__ double       s_part[4][4];
    __shared__ unsigned int s_w[256];    // fetched 32-bit halves
    __shared__ double       s_xm[NC];    // reassembled channel means
    __shared__ float        s_tau;

    const v4f* __restrict__ x4 = (const v4f*)x;
    v4f* __restrict__ o4       = (v4f*)out;

    v4f mem[4];
    #pragma unroll
    for (int p = 0; p < 4; ++p) mem[p] = (v4f){0.f, 0.f, 0.f, 0.f};

    float tau = 0.5f;                    // TAU0

    v4f xv[4];
    #pragma unroll
    for (int p = 0; p < 4; ++p)
        xv[p] = __builtin_nontemporal_load(x4 + ((b * NT + 0) * NC + c0 + p) * NQ + tid);

    for (int t = 0; t < NT; ++t) {
        double psum[4];
        #pragma unroll
        for (int p = 0; p < 4; ++p) {
            v4f m = mem[p];
            m.x = fmaf(m.x, tau, xv[p].x);
            m.y = fmaf(m.y, tau, xv[p].y);
            m.z = fmaf(m.z, tau, xv[p].z);
            m.w = fmaf(m.w, tau, xv[p].w);
            psum[p] = ((double)m.x + (double)m.y) + ((double)m.z + (double)m.w);
            v4f sp;
            sp.x = (m.x > 1.0f) ? 1.0f : 0.0f;   // zif(mem-1): exact (Sterbenz)
            sp.y = (m.y > 1.0f) ? 1.0f : 0.0f;
            sp.z = (m.z > 1.0f) ? 1.0f : 0.0f;
            sp.w = (m.w > 1.0f) ? 1.0f : 0.0f;
            __builtin_nontemporal_store(sp, o4 + ((b * NT + t) * NC + c0 + p) * NQ + tid);
            m.x = (m.x > 1.0f) ? 0.0f : m.x;     // (1-spike)*mem
            m.y = (m.y > 1.0f) ? 0.0f : m.y;
            m.z = (m.z > 1.0f) ? 0.0f : m.z;
            m.w = (m.w > 1.0f) ? 0.0f : m.w;
            mem[p] = m;
        }

        // prefetch next x so the loads fly across the reduce + barrier
        if (t + 1 < NT) {
            #pragma unroll
            for (int p = 0; p < 4; ++p)
                xv[p] = __builtin_nontemporal_load(
                    x4 + ((b * NT + (t + 1)) * NC + c0 + p) * NQ + tid);
        }

        #pragma unroll
        for (int p = 0; p < 4; ++p) {
            double s = psum[p];
            #pragma unroll
            for (int off = 32; off > 0; off >>= 1) s += __shfl_down(s, off);
            if (ln == 0) s_part[p][wv] = s;
        }
        __syncthreads();
        if (tid < 4) {
            double s = (s_part[tid][0] + s_part[tid][1]) +
                       (s_part[tid][2] + s_part[tid][3]);
            double mean = s * (1.0 / 1024.0);
            unsigned long long bits = __double_as_longlong(mean);
            unsigned long long tag  = ((unsigned long long)(t + 1)) << 32;
            const int base = (((t & 1) * (NB * NC)) + b * NC + c0 + tid) * 2;
            // LLC-direct publish; per-word seq tag makes freshness
            // self-validating (no reliance on store-ack == LLC-complete)
            __hip_atomic_store(&g_xw[base + 0], tag | (bits & 0xffffffffull),
                               __ATOMIC_RELAXED, __HIP_MEMORY_SCOPE_AGENT);
            __hip_atomic_store(&g_xw[base + 1], tag | (bits >> 32),
                               __ATOMIC_RELAXED, __HIP_MEMORY_SCOPE_AGENT);
        }
        __syncthreads();   // publish issued + vmcnt drained before arrive

        if (t == NT - 1) break;

        // ---- per-batch barrier: relaxed LLC atomics only, zero fences ----
        // Still required for WAR safety of the (t&1) double buffer: a block
        // cannot reach step t+2's same-parity publish until every block of
        // the batch arrived at t+1, i.e. after their step-t reads.
        if (tid == 0) {
            __hip_atomic_fetch_add(&g_arrive[b * PADI], 1,
                                   __ATOMIC_RELAXED, __HIP_MEMORY_SCOPE_AGENT);
            const int target = 32 * (t + 1);     // monotonic; init kernel zeroes
            while (__hip_atomic_load(&g_arrive[b * PADI],
                                     __ATOMIC_RELAXED, __HIP_MEMORY_SCOPE_AGENT) < target)
                __builtin_amdgcn_s_sleep(2);
        }
        __syncthreads();

        // ---- seq-validated parallel fetch: ONE LLC round-trip (typ.) ----
        // lane tid -> word (channel tid>>1, half tid&1). Spin until the
        // word's embedded seq == t+1; normally satisfied on the first load
        // since the arrive barrier already ordered the publish issue.
        {
            const int idx = (((t & 1) * (NB * NC)) + b * NC + (tid >> 1)) * 2
                            + (tid & 1);
            const unsigned int want = (unsigned int)(t + 1);
            unsigned long long w;
            for (;;) {
                w = __hip_atomic_load(&g_xw[idx], __ATOMIC_RELAXED,
                                      __HIP_MEMORY_SCOPE_AGENT);
                if ((unsigned int)(w >> 32) == want) break;
                __builtin_amdgcn_s_sleep(1);
            }
            s_w[tid] = (unsigned int)w;
        }
        __syncthreads();
        if (tid < NC) {
            unsigned long long bits =
                ((unsigned long long)s_w[2 * tid + 1] << 32) | s_w[2 * tid];
            s_xm[tid] = __longlong_as_double(bits);   // exact double bits
        }
        __syncthreads();

        // tiny MLP (128->32->1), recomputed per block for its own batch.
        // s_xm reads are same-address broadcasts (no bank conflicts); w1 row
        // is per-lane contiguous float4 (L1-resident). Summation order is
        // identical to the verified kernel: cc = 0..127 ascending.
        double e = 0.0;
        if (tid < CRED) {
            const v4f* __restrict__ w1v = (const v4f*)(w1 + tid * NC);
            double acc = (double)b1[tid];
            #pragma unroll
            for (int q = 0; q < NC / 4; ++q) {
                v4f wq = w1v[q];
                acc += s_xm[4 * q + 0] * (double)wq.x;
                acc += s_xm[4 * q + 1] * (double)wq.y;
                acc += s_xm[4 * q + 2] * (double)wq.z;
                acc += s_xm[4 * q + 3] * (double)wq.w;
            }
            double emb = acc > 0.0 ? acc : 0.0;
            e = emb * (double)w2[tid];
        }
        #pragma unroll
        for (int off = 32; off > 0; off >>= 1) e += __shfl_down(e, off);
        if (tid == 0) {
            double z = e + (double)b2[0];
            s_tau = (float)(1.0 / (1.0 + exp(-z)));
        }
        __syncthreads();
        tau = s_tau;
    }
}

extern "C" void kernel_launch(void* const* d_in, const int* in_sizes, int n_in,
                              void* d_out, int out_size, void* d_ws, size_t ws_size,
                              hipStream_t stream) {
    const float* x  = (const float*)d_in[0];
    const float* w1 = (const float*)d_in[1];
    const float* b1 = (const float*)d_in[2];
    const float* w2 = (const float*)d_in[3];
    const float* b2 = (const float*)d_in[4];
    float* out      = (float*)d_out;

    // zero word buffer + arrival counters (stream-ordered before main kernel)
    hipLaunchKernelGGL(lif_init, dim3((NWORDS + 255) / 256), dim3(256),
                       0, stream);
    // plain launch — no cooperative protocol overhead
    hipLaunchKernelGGL(dynamic_lif, dim3(NB * NC / 4), dim3(256), 0, stream,
                       x, w1, b1, w2, b2, out);
}

// Round 7
// 276.896 us; speedup vs baseline: 1.0282x; 1.0282x over previous
//
#include <hip/hip_runtime.h>

typedef float v4f __attribute__((ext_vector_type(4)));

#define NB   32     // batch
#define NT   8      // timesteps
#define NC   128    // channels
#define NQ   256    // float4s per (H*W)=1024 plane
#define CRED 32     // C/red

// Cross-block mean publish: each channel mean (double) is split into two
// 64-bit words:  word = (seq << 32) | 32-bit-half-of-double-bits, seq = t+1.
// Data and version share ONE atomic location -> freshness is self-validating
// (no reliance on store-ack == LLC-complete; that was the R0 failure).
// R2: one buffer slice PER STEP (no reuse -> no WAR hazard), which makes the
// per-batch arrive barrier redundant: consumers spin directly on the data
// words, so the poll IS the fetch (collapses arrive-RT + fetch-RT into one
// LLC observation). Zeroed per launch so seq=0 is invalid across replays.
#define NWORDS (NT * NB * NC * 2)   // step x batch x channel x {lo,hi}

__device__ unsigned long long g_xw[NWORDS];          // (seq<<32 | half) words

__global__ __launch_bounds__(256)
void lif_init() {
    int i = threadIdx.x + blockIdx.x * blockDim.x;
    if (i < NWORDS) g_xw[i] = 0ull;
}

// Raw barrier: LDS-only drain (lgkmcnt), NO vmcnt(0). Fused into one asm so
// no LDS access can be hoisted between the wait and the barrier. This keeps
// the nontemporal out-stores fire-and-forget and lets the x-prefetch loads
// fly across the barrier + MLP phase (a __syncthreads would drain both).
#define LDS_BARRIER() asm volatile("s_waitcnt lgkmcnt(0)\n\ts_barrier" ::: "memory")

// ---------------------------------------------------------------------------
// Single persistent kernel, plain launch. 1024 blocks (one per (b, 4-channel
// group)), 256 threads; mem state in registers. Per step: fused
// fma/spike/reset/store + plane-mean publish (seq-tagged LLC atomic words),
// then a seq-validated 256-lane spin-fetch into LDS (no arrive barrier) and
// a redundant per-block 128->32->1 MLP for the next tau. Mean double bits
// are reassembled exactly, so tau is bit-identical to the verified kernel.
// Co-residency: 1024 blocks @ 56 VGPR -> 8 blocks/CU capacity, 4 needed;
// fast blocks may run ahead (per-step buffers), spin cannot deadlock.
// ---------------------------------------------------------------------------
__global__ __launch_bounds__(256, 4)
void dynamic_lif(const float* __restrict__ x,
                 const float* __restrict__ w1,
                 const float* __restrict__ b1,
                 const float* __restrict__ w2,
                 const float* __restrict__ b2,
                 float* __restrict__ out)
{
    const int bid = blockIdx.x;          // 0..1023
    const int b   = bid >> 5;            // batch
    const int c0  = (bid & 31) << 2;     // first of 4 channels
    const int tid = threadIdx.x;
    const int wv  = tid >> 6;
    const int ln  = tid & 63;

    __shared__ double       s_part[4][4];
    __shared__ unsigned int s_w[256];    // fetched 32-bit halves
    __shared__ float        s_tau;

    const v4f* __restrict__ x4 = (const v4f*)x;
    v4f* __restrict__ o4       = (v4f*)out;

    v4f mem[4];
    #pragma unroll
    for (int p = 0; p < 4; ++p) mem[p] = (v4f){0.f, 0.f, 0.f, 0.f};

    float tau = 0.5f;                    // TAU0

    v4f xv[4];
    #pragma unroll
    for (int p = 0; p < 4; ++p)
        xv[p] = __builtin_nontemporal_load(x4 + ((b * NT + 0) * NC + c0 + p) * NQ + tid);

    for (int t = 0; t < NT; ++t) {
        double psum[4];
        #pragma unroll
        for (int p = 0; p < 4; ++p) {
            v4f m = mem[p];
            m.x = fmaf(m.x, tau, xv[p].x);
            m.y = fmaf(m.y, tau, xv[p].y);
            m.z = fmaf(m.z, tau, xv[p].z);
            m.w = fmaf(m.w, tau, xv[p].w);
            psum[p] = ((double)m.x + (double)m.y) + ((double)m.z + (double)m.w);
            v4f sp;
            sp.x = (m.x > 1.0f) ? 1.0f : 0.0f;   // zif(mem-1): exact (Sterbenz)
            sp.y = (m.y > 1.0f) ? 1.0f : 0.0f;
            sp.z = (m.z > 1.0f) ? 1.0f : 0.0f;
            sp.w = (m.w > 1.0f) ? 1.0f : 0.0f;
            __builtin_nontemporal_store(sp, o4 + ((b * NT + t) * NC + c0 + p) * NQ + tid);
            m.x = (m.x > 1.0f) ? 0.0f : m.x;     // (1-spike)*mem
            m.y = (m.y > 1.0f) ? 0.0f : m.y;
            m.z = (m.z > 1.0f) ? 0.0f : m.z;
            m.w = (m.w > 1.0f) ? 0.0f : m.w;
            mem[p] = m;
        }

        // prefetch next x; with LDS-only barriers these loads stay in flight
        // across the reduce + publish + poll + MLP phases
        if (t + 1 < NT) {
            #pragma unroll
            for (int p = 0; p < 4; ++p)
                xv[p] = __builtin_nontemporal_load(
                    x4 + ((b * NT + (t + 1)) * NC + c0 + p) * NQ + tid);
        }

        #pragma unroll
        for (int p = 0; p < 4; ++p) {
            double s = psum[p];
            #pragma unroll
            for (int off = 32; off > 0; off >>= 1) s += __shfl_down(s, off);
            if (ln == 0) s_part[p][wv] = s;
        }
        LDS_BARRIER();                   // s_part visible to wave 0

        if (t == NT - 1) break;

        if (tid < 4) {
            double s = (s_part[tid][0] + s_part[tid][1]) +
                       (s_part[tid][2] + s_part[tid][3]);
            double mean = s * (1.0 / 1024.0);
            unsigned long long bits = __double_as_longlong(mean);
            unsigned long long tag  = ((unsigned long long)(t + 1)) << 32;
            const int base = ((t * NB + b) * NC + c0 + tid) * 2;
            // LLC-direct publish, fire-and-forget: per-word seq tag makes
            // freshness self-validating, so no drain / no ordering needed
            __hip_atomic_store(&g_xw[base + 0], tag | (bits & 0xffffffffull),
                               __ATOMIC_RELAXED, __HIP_MEMORY_SCOPE_AGENT);
            __hip_atomic_store(&g_xw[base + 1], tag | (bits >> 32),
                               __ATOMIC_RELAXED, __HIP_MEMORY_SCOPE_AGENT);
        }
        // no barrier: within-wave program order guarantees wave 0 publishes
        // before it polls; other waves just spin until the words land

        // ---- seq-validated spin-fetch: the poll IS the fetch ----
        // lane tid -> word (channel tid>>1, half tid&1); spin until the
        // word's embedded seq == t+1 (i.e. until the publisher's store
        // landed at the LLC), then stash the 32-bit half in LDS.
        {
            const int idx = ((t * NB + b) * NC + (tid >> 1)) * 2 + (tid & 1);
            const unsigned int want = (unsigned int)(t + 1);
            unsigned long long w;
            for (;;) {
                w = __hip_atomic_load(&g_xw[idx], __ATOMIC_RELAXED,
                                      __HIP_MEMORY_SCOPE_AGENT);
                if ((unsigned int)(w >> 32) == want) break;
                __builtin_amdgcn_s_sleep(2);
            }
            s_w[tid] = (unsigned int)w;
        }
        LDS_BARRIER();                   // s_w visible to wave 0

        // tiny MLP (128->32->1), recomputed per block for its own batch.
        // s_w reads are same-address broadcasts (no bank conflicts); w1 row
        // is per-lane contiguous float4 (L1-resident). Mean double bits are
        // reassembled exactly; summation order identical to the verified
        // kernel: cc = 0..127 ascending.
        double e = 0.0;
        if (tid < CRED) {
            const v4f* __restrict__ w1v = (const v4f*)(w1 + tid * NC);
            double acc = (double)b1[tid];
            #pragma unroll
            for (int q = 0; q < NC / 4; ++q) {
                v4f wq = w1v[q];
                #pragma unroll
                for (int k = 0; k < 4; ++k) {
                    const int c = 4 * q + k;
                    unsigned long long bits =
                        ((unsigned long long)s_w[2 * c + 1] << 32) | s_w[2 * c];
                    double xm = __longlong_as_double(bits);
                    acc += xm * (double)((k == 0) ? wq.x : (k == 1) ? wq.y
                                         : (k == 2) ? wq.z : wq.w);
                }
            }
            double emb = acc > 0.0 ? acc : 0.0;
            e = emb * (double)w2[tid];
        }
        #pragma unroll
        for (int off = 32; off > 0; off >>= 1) e += __shfl_down(e, off);
        if (tid == 0) {
            double z = e + (double)b2[0];
            s_tau = (float)(1.0 / (1.0 + exp(-z)));
        }
        LDS_BARRIER();                   // s_tau visible to all waves
        tau = s_tau;
    }
}

extern "C" void kernel_launch(void* const* d_in, const int* in_sizes, int n_in,
                              void* d_out, int out_size, void* d_ws, size_t ws_size,
                              hipStream_t stream) {
    const float* x  = (const float*)d_in[0];
    const float* w1 = (const float*)d_in[1];
    const float* b1 = (const float*)d_in[2];
    const float* w2 = (const float*)d_in[3];
    const float* b2 = (const float*)d_in[4];
    float* out      = (float*)d_out;

    // zero the seq-tagged word buffer (stream-ordered before the main kernel)
    hipLaunchKernelGGL(lif_init, dim3((NWORDS + 255) / 256), dim3(256),
                       0, stream);
    // plain launch — no cooperative protocol overhead
    hipLaunchKernelGGL(dynamic_lif, dim3(NB * NC / 4), dim3(256), 0, stream,
                       x, w1, b1, w2, b2, out);
}

// Round 10
// 265.769 us; speedup vs baseline: 1.0712x; 1.0419x over previous
//
#include <hip/hip_runtime.h>

typedef float v4f __attribute__((ext_vector_type(4)));

#define NB   32     // batch
#define NT   8      // timesteps
#define NC   128    // channels
#define NQ   256    // float4s per (H*W)=1024 plane
#define CRED 32     // C/red

// Cross-block mean publish: each channel mean (double) is split into two
// 64-bit words:  word = (seq << 32) | 32-bit-half-of-double-bits, seq = t+1.
// Data and version share ONE atomic location -> freshness is self-validating
// (no reliance on store-ack == LLC-complete; that was the R0 failure).
// One buffer slice PER STEP (write-once -> no WAR hazard) -> no arrive
// barrier: consumers spin directly on the data words (the poll IS the
// fetch). Zeroed per launch so seq=0 is invalid across graph replays.
#define NWORDS (NT * NB * NC * 2)   // step x batch x channel x {lo,hi}

__device__ unsigned long long g_xw[NWORDS];          // (seq<<32 | half) words

__global__ __launch_bounds__(256)
void lif_init() {
    int i = threadIdx.x + blockIdx.x * blockDim.x;
    if (i < NWORDS) g_xw[i] = 0ull;
}

// Raw barrier: LDS-only drain (lgkmcnt), NO vmcnt(0). Fused into one asm so
// no LDS access can be hoisted between the wait and the barrier. Keeps the
// nontemporal out-stores fire-and-forget and lets prefetch loads stay in
// flight across the barrier + MLP phase.
#define LDS_BARRIER() asm volatile("s_waitcnt lgkmcnt(0)\n\ts_barrier" ::: "memory")

// ---------------------------------------------------------------------------
// R3 reorder: PUBLISH FIRST, STORE LATER. R2's counters (97.3 us, HBM 27%,
// VALU 11%) showed the sync-protocol fix bought only 10 us -> the consumers
// were not waiting on protocol round-trips; they were waiting on the
// publisher's store queue: each wave issued 16 nontemporal spike stores + 4
// prefetch loads BEFORE the 32-byte publish, so the means landed at the LLC
// behind a multi-us HBM write drain (16.8 MB/step GPU-wide). This version
// computes fma+psum only, reduces, publishes (first VMEM ops of the step for
// the publishing wave), and THEN does prefetch + spike + NT-store + reset in
// the window where the block would otherwise idle-poll for its siblings.
// Identical op order for fma/psum/reduce/MLP/sigmoid -> spikes and tau are
// bit-identical to the harness-verified R1/R2 kernels.
// Co-residency: 1024 blocks @ ~56 VGPR -> 8 blocks/CU capacity, 4 needed;
// fast blocks may run ahead (per-step buffers), spin cannot deadlock.
// ---------------------------------------------------------------------------
__global__ __launch_bounds__(256, 4)
void dynamic_lif(const float* __restrict__ x,
                 const float* __restrict__ w1,
                 const float* __restrict__ b1,
                 const float* __restrict__ w2,
                 const float* __restrict__ b2,
                 float* __restrict__ out)
{
    const int bid = blockIdx.x;          // 0..1023
    const int b   = bid >> 5;            // batch
    const int c0  = (bid & 31) << 2;     // first of 4 channels
    const int tid = threadIdx.x;
    const int wv  = tid >> 6;
    const int ln  = tid & 63;

    __shared__ double       s_part[4][4];
    __shared__ unsigned int s_w[256];    // fetched 32-bit halves
    __shared__ float        s_tau;

    const v4f* __restrict__ x4 = (const v4f*)x;
    v4f* __restrict__ o4       = (v4f*)out;

    v4f mem[4];
    #pragma unroll
    for (int p = 0; p < 4; ++p) mem[p] = (v4f){0.f, 0.f, 0.f, 0.f};

    float tau = 0.5f;                    // TAU0

    v4f xv[4];
    #pragma unroll
    for (int p = 0; p < 4; ++p)
        xv[p] = __builtin_nontemporal_load(x4 + ((b * NT + 0) * NC + c0 + p) * NQ + tid);

    for (int t = 0; t < NT; ++t) {
        // ---- phase A: fma + plane-sum ONLY (no stores yet) ----
        // mem[p] holds the PRE-reset membrane value through the publish.
        double psum[4];
        #pragma unroll
        for (int p = 0; p < 4; ++p) {
            v4f m = mem[p];
            m.x = fmaf(m.x, tau, xv[p].x);
            m.y = fmaf(m.y, tau, xv[p].y);
            m.z = fmaf(m.z, tau, xv[p].z);
            m.w = fmaf(m.w, tau, xv[p].w);
            psum[p] = ((double)m.x + (double)m.y) + ((double)m.z + (double)m.w);
            mem[p] = m;
        }

        #pragma unroll
        for (int p = 0; p < 4; ++p) {
            double s = psum[p];
            #pragma unroll
            for (int off = 32; off > 0; off >>= 1) s += __shfl_down(s, off);
            if (ln == 0) s_part[p][wv] = s;
        }
        LDS_BARRIER();                   // s_part visible to wave 0

        // ---- publish: FIRST VMEM ops of this step for wave 0 ----
        if (t < NT - 1 && tid < 4) {
            double s = (s_part[tid][0] + s_part[tid][1]) +
                       (s_part[tid][2] + s_part[tid][3]);
            double mean = s * (1.0 / 1024.0);
            unsigned long long bits = __double_as_longlong(mean);
            unsigned long long tag  = ((unsigned long long)(t + 1)) << 32;
            const int base = ((t * NB + b) * NC + c0 + tid) * 2;
            // LLC-direct, fire-and-forget; seq tag self-validates freshness
            __hip_atomic_store(&g_xw[base + 0], tag | (bits & 0xffffffffull),
                               __ATOMIC_RELAXED, __HIP_MEMORY_SCOPE_AGENT);
            __hip_atomic_store(&g_xw[base + 1], tag | (bits >> 32),
                               __ATOMIC_RELAXED, __HIP_MEMORY_SCOPE_AGENT);
        }

        // ---- phase B (off the critical path): prefetch, spike, store ----
        if (t + 1 < NT) {
            #pragma unroll
            for (int p = 0; p < 4; ++p)
                xv[p] = __builtin_nontemporal_load(
                    x4 + ((b * NT + (t + 1)) * NC + c0 + p) * NQ + tid);
        }
        #pragma unroll
        for (int p = 0; p < 4; ++p) {
            v4f m = mem[p];
            v4f sp;
            sp.x = (m.x > 1.0f) ? 1.0f : 0.0f;   // zif(mem-1): exact (Sterbenz)
            sp.y = (m.y > 1.0f) ? 1.0f : 0.0f;
            sp.z = (m.z > 1.0f) ? 1.0f : 0.0f;
            sp.w = (m.w > 1.0f) ? 1.0f : 0.0f;
            __builtin_nontemporal_store(sp, o4 + ((b * NT + t) * NC + c0 + p) * NQ + tid);
            m.x = (m.x > 1.0f) ? 0.0f : m.x;     // (1-spike)*mem
            m.y = (m.y > 1.0f) ? 0.0f : m.y;
            m.z = (m.z > 1.0f) ? 0.0f : m.z;
            m.w = (m.w > 1.0f) ? 0.0f : m.w;
            mem[p] = m;
        }

        if (t == NT - 1) break;

        // ---- seq-validated spin-fetch: the poll IS the fetch ----
        // lane tid -> word (channel tid>>1, half tid&1); spin until the
        // word's embedded seq == t+1, then stash the 32-bit half in LDS.
        {
            const int idx = ((t * NB + b) * NC + (tid >> 1)) * 2 + (tid & 1);
            const unsigned int want = (unsigned int)(t + 1);
            unsigned long long w;
            for (;;) {
                w = __hip_atomic_load(&g_xw[idx], __ATOMIC_RELAXED,
                                      __HIP_MEMORY_SCOPE_AGENT);
                if ((unsigned int)(w >> 32) == want) break;
                __builtin_amdgcn_s_sleep(1);
            }
            s_w[tid] = (unsigned int)w;
        }
        LDS_BARRIER();                   // s_w visible to wave 0

        // tiny MLP (128->32->1), recomputed per block for its own batch.
        // s_w reads are same-address broadcasts (no bank conflicts); w1 row
        // is per-lane contiguous float4 (L1-resident). Mean double bits are
        // reassembled exactly; summation order identical to the verified
        // kernel: cc = 0..127 ascending.
        double e = 0.0;
        if (tid < CRED) {
            const v4f* __restrict__ w1v = (const v4f*)(w1 + tid * NC);
            double acc = (double)b1[tid];
            #pragma unroll
            for (int q = 0; q < NC / 4; ++q) {
                v4f wq = w1v[q];
                #pragma unroll
                for (int k = 0; k < 4; ++k) {
                    const int c = 4 * q + k;
                    unsigned long long bits =
                        ((unsigned long long)s_w[2 * c + 1] << 32) | s_w[2 * c];
                    double xm = __longlong_as_double(bits);
                    acc += xm * (double)((k == 0) ? wq.x : (k == 1) ? wq.y
                                         : (k == 2) ? wq.z : wq.w);
                }
            }
            double emb = acc > 0.0 ? acc : 0.0;
            e = emb * (double)w2[tid];
        }
        #pragma unroll
        for (int off = 32; off > 0; off >>= 1) e += __shfl_down(e, off);
        if (tid == 0) {
            double z = e + (double)b2[0];
            s_tau = (float)(1.0 / (1.0 + exp(-z)));
        }
        LDS_BARRIER();                   // s_tau visible to all waves
        tau = s_tau;
    }
}

extern "C" void kernel_launch(void* const* d_in, const int* in_sizes, int n_in,
                              void* d_out, int out_size, void* d_ws, size_t ws_size,
                              hipStream_t stream) {
    const float* x  = (const float*)d_in[0];
    const float* w1 = (const float*)d_in[1];
    const float* b1 = (const float*)d_in[2];
    const float* w2 = (const float*)d_in[3];
    const float* b2 = (const float*)d_in[4];
    float* out      = (float*)d_out;

    // zero the seq-tagged word buffer (stream-ordered before the main kernel)
    hipLaunchKernelGGL(lif_init, dim3((NWORDS + 255) / 256), dim3(256),
                       0, stream);
    // plain launch — no cooperative protocol overhead
    hipLaunchKernelGGL(dynamic_lif, dim3(NB * NC / 4), dim3(256), 0, stream,
                       x, w1, b1, w2, b2, out);
}